// Round 9
// baseline (158.560 us; speedup 1.0000x reference)
//
#include <hip/hip_runtime.h>

// N=100000, E=1600000, D=64, C=16
#define DD 64
#define CC 16
#define EPSILON 0.1f
#define GAMMA 0.1f
#define BSH 6            // log2(nodes per fine bucket)
#define BSZ 64
#define CAP 1280         // bucket capacity for CSR (mean 1024, +8 sigma)
#define NFB 2048         // fine buckets (>= ceil(N/64) = 1563)
#define NREP 8           // reservation replicas (blockIdx & 7)
#define SEGF 192         // per-(bucket,replica) segment capacity (mean 100, +9s)
#define PAD 68           // fp32 R0 row stride: 272 B, 16B-aligned rows
#define PADW 65
#define FCHUNK 8192      // edges per K1 block (196 blocks)
#define FTHR 512

typedef float v2f __attribute__((ext_vector_type(2)));
typedef __attribute__((ext_vector_type(8))) short short8v;   // 8 bf16
typedef __attribute__((ext_vector_type(4))) float f32x4;

// fp32 -> bf16 round-to-nearest-even (finite inputs only)
static __device__ inline short f2bf(float f) {
    unsigned u = __builtin_bit_cast(unsigned, f);
    unsigned r = (u + 0x7FFFu + ((u >> 16) & 1u)) >> 16;
    return (short)r;
}

// ---------------------------------------------------------------------------
// K1: SINGLE-PASS fine binning (replaces coarse+fine two-level).
// Per 8192-edge block: LDS histogram over all 2048 fine buckets -> one
// global reservation per (bucket, replica=blockIdx&7)  [chain depth 196/8
// ~ 25: r8 proved same-address chains are the serial cost; r3 proved
// same-line different-address atomics are fine unpadded] -> direct store
// into the private segment. Mean 4 consecutive entries per (bucket,block)
// => 16B store clusters, bounded write amplification.
// Plus grid-stride x -> fp8 e4m3 conversion and (block 0) weight fold into
// bf16 MFMA-fragment order.
// Entry: src(17) | dst_node_local(6) << 17.
__global__ __launch_bounds__(FTHR) void bin_conv(
        const int* __restrict__ ei, int* __restrict__ gcnt,
        unsigned* __restrict__ binned, int E,
        const float* __restrict__ x, unsigned* __restrict__ x_q, int N,
        const float* __restrict__ Wrel, const float* __restrict__ Wroot,
        const float* __restrict__ Wanti, const float* __restrict__ brel,
        const float* __restrict__ banti,
        unsigned short* __restrict__ Bp, float* __restrict__ bc) {
    __shared__ int hist[NFB], gbase[NFB], cur[NFB];   // 24 KB
    const int t = threadIdx.x;
    const int rep = blockIdx.x & (NREP - 1);
    for (int i = t; i < NFB; i += FTHR) { hist[i] = 0; cur[i] = 0; }
    __syncthreads();
    const int e0 = blockIdx.x * FCHUNK;
    int srcv[16], dstv[16];
#pragma unroll
    for (int jj = 0; jj < 4; ++jj) {
        int e4 = e0 + 4 * (t + FTHR * jj);
        if (e4 + 4 <= E) {                   // aligned int4 loads
            int4 s4 = *(const int4*)&ei[e4];
            int4 d4 = *(const int4*)&ei[E + e4];
            srcv[4 * jj + 0] = s4.x; srcv[4 * jj + 1] = s4.y;
            srcv[4 * jj + 2] = s4.z; srcv[4 * jj + 3] = s4.w;
            dstv[4 * jj + 0] = d4.x; dstv[4 * jj + 1] = d4.y;
            dstv[4 * jj + 2] = d4.z; dstv[4 * jj + 3] = d4.w;
        } else {
#pragma unroll
            for (int i = 0; i < 4; ++i) {
                int e = e4 + i;
                if (e < E) { srcv[4 * jj + i] = ei[e]; dstv[4 * jj + i] = ei[E + e]; }
                else dstv[4 * jj + i] = -1;
            }
        }
    }
#pragma unroll
    for (int i = 0; i < 16; ++i)
        if (dstv[i] >= 0) atomicAdd(&hist[dstv[i] >> BSH], 1);
    __syncthreads();
    for (int i = t; i < NFB; i += FTHR) {
        int h = hist[i];
        gbase[i] = h ? atomicAdd(&gcnt[i * NREP + rep], h) : 0;
    }
    __syncthreads();
#pragma unroll
    for (int i = 0; i < 16; ++i) {
        if (dstv[i] >= 0) {
            int fb = dstv[i] >> BSH;
            int pos = gbase[fb] + atomicAdd(&cur[fb], 1);
            if (pos < SEGF)
                binned[((size_t)fb * NREP + rep) * SEGF + pos] =
                    (unsigned)srcv[i] |
                    ((unsigned)(dstv[i] & (BSZ - 1)) << 17);
        }
    }
    // ---- weight fold -> bf16 fragment-packed (block 0 only) ----
    if (blockIdx.x == 0) {
        for (int idx = t; idx < 16 * 64 * 8; idx += FTHR) {
            int j = idx & 7, l = (idx >> 3) & 63;
            int nt = (idx >> 9) & 3, ks = idx >> 11;
            int k = ks * 32 + ((l >> 4) << 3) + j;
            int d = nt * 16 + (l & 15);
            float v;
            if (k < 64) {
                v = Wrel[d * 64 + k];
            } else {
                int j2 = k - 64;
                v = Wroot[d * 64 + j2] + Wanti[d * 64 + j2] - Wanti[j2 * 64 + d];
                if (d == j2) v -= GAMMA;
            }
            Bp[idx] = (unsigned short)f2bf(v);
        }
        if (t < 64) bc[t] = brel[t] + banti[t];
    }
    // ---- fused x -> fp8 conversion ----
    const float4* x4 = (const float4*)x;
    const int M = N * (DD / 4);
    const int G = gridDim.x * FTHR;
    for (int i = blockIdx.x * FTHR + t; i < M; i += G) {
        float4 a = x4[i];
        int r = __builtin_amdgcn_cvt_pk_fp8_f32(a.x, a.y, 0, false);
        r = __builtin_amdgcn_cvt_pk_fp8_f32(a.z, a.w, r, true);
        x_q[i] = (unsigned)r;
    }
}

// ---------------------------------------------------------------------------
// K2 mega (r8 MFMA version; input now 8 replica segments per bucket).
// CSR build (per-segment passes, unrolled constant indices) + fp8 gather
// (8-deep pipeline) + MFMA dense h = [agg | x] @ B + fused epilogues.
__global__ __launch_bounds__(512, 6) void mega(
        const float* __restrict__ x, const unsigned* __restrict__ x_q,
        const int* __restrict__ gcnt, const unsigned* __restrict__ binned,
        const unsigned short* __restrict__ Bp, const float* __restrict__ bc,
        const float* __restrict__ Wlin, const float* __restrict__ blin,
        float* __restrict__ out, int N) {
    __shared__ float R0[BSZ * PAD];         // 17.4 KB: agg -> x -> xn
    __shared__ float wl_sh[CC * PADW];      // 4.2 KB
    __shared__ int csr[CAP];                // 5.1 KB
    __shared__ int deg[BSZ], offs[BSZ], cur[BSZ];

    const int t = threadIdx.x;
    const int b = blockIdx.x;
    const int nb0 = b << BSH;
    const unsigned* segbase = binned + (size_t)b * NREP * SEGF;

    int cnt_r[NREP];
    {
        int total = 0;
#pragma unroll
        for (int r = 0; r < NREP; ++r) {
            int c = gcnt[b * NREP + r];
            if (c > SEGF) c = SEGF;
            if (total + c > CAP) c = CAP - total;
            cnt_r[r] = c;
            total += c;
        }
    }

#pragma unroll
    for (int i = 0; i < 2; ++i) {
        int idx = t + 512 * i;
        wl_sh[(idx >> 6) * PADW + (idx & 63)] = Wlin[idx];
    }
    if (t < BSZ) deg[t] = 0;
    __syncthreads();
#pragma unroll
    for (int r = 0; r < NREP; ++r) {
        const unsigned* seg = segbase + r * SEGF;
        for (int i = t; i < cnt_r[r]; i += 512)
            atomicAdd(&deg[seg[i] >> 17], 1);
    }
    __syncthreads();
    if (t < 64) {                           // single-wave prefix scan
        int v = deg[t];
#pragma unroll
        for (int off = 1; off < 64; off <<= 1) {
            int u = __shfl_up(v, off, 64);
            if (t >= off) v += u;
        }
        offs[t] = v - deg[t];
        cur[t] = v - deg[t];
    }
    __syncthreads();
#pragma unroll
    for (int r = 0; r < NREP; ++r) {
        const unsigned* seg = segbase + r * SEGF;
        for (int i = t; i < cnt_r[r]; i += 512) {
            unsigned en = seg[i];
            int pos = atomicAdd(&cur[en >> 17], 1);
            csr[pos] = (int)(en & 0x1FFFF);
        }
    }
    __syncthreads();

    // fp8 gather, 8-deep pipeline
    {
        const int g = t >> 3, q = t & 7;
        const uint2* xq2 = (const uint2*)x_q;   // 8 fp8 per slot; row = 8 slots
        const int i0 = offs[g], dc = deg[g];
        float a[8];
#pragma unroll
        for (int r = 0; r < 8; ++r) a[r] = 0.f;
        int i = 0;
        for (; i + 8 <= dc; i += 8) {
            int s0 = csr[i0 + i + 0], s1 = csr[i0 + i + 1];
            int s2 = csr[i0 + i + 2], s3 = csr[i0 + i + 3];
            int s4 = csr[i0 + i + 4], s5 = csr[i0 + i + 5];
            int s6 = csr[i0 + i + 6], s7 = csr[i0 + i + 7];
            uint2 v0 = xq2[s0 * 8 + q];
            uint2 v1 = xq2[s1 * 8 + q];
            uint2 v2 = xq2[s2 * 8 + q];
            uint2 v3 = xq2[s3 * 8 + q];
            uint2 v4 = xq2[s4 * 8 + q];
            uint2 v5 = xq2[s5 * 8 + q];
            uint2 v6 = xq2[s6 * 8 + q];
            uint2 v7 = xq2[s7 * 8 + q];
            v2f f;
#define ACC8(v)                                                               \
            f = __builtin_amdgcn_cvt_pk_f32_fp8((v).x, false); a[0] += f.x; a[1] += f.y; \
            f = __builtin_amdgcn_cvt_pk_f32_fp8((v).x, true);  a[2] += f.x; a[3] += f.y; \
            f = __builtin_amdgcn_cvt_pk_f32_fp8((v).y, false); a[4] += f.x; a[5] += f.y; \
            f = __builtin_amdgcn_cvt_pk_f32_fp8((v).y, true);  a[6] += f.x; a[7] += f.y;
            ACC8(v0); ACC8(v1); ACC8(v2); ACC8(v3);
            ACC8(v4); ACC8(v5); ACC8(v6); ACC8(v7);
        }
        for (; i < dc; ++i) {
            int s0 = csr[i0 + i];
            uint2 v0 = xq2[s0 * 8 + q];
            v2f f;
            ACC8(v0);
#undef ACC8
        }
        float* row = &R0[g * PAD + 8 * q];
#pragma unroll
        for (int r = 0; r < 8; ++r) row[r] = a[r];
    }
    __syncthreads();

    // ---- MFMA dense ----
    const int lane = t & 63;
    const int w = t >> 6;                   // wave 0..7
    const int nt = w & 3, mbase = (w >> 2) * 32;
    const int arow = (mbase + (lane & 15)) * PAD + ((lane >> 4) << 3);
    f32x4 acc0 = {0.f, 0.f, 0.f, 0.f}, acc1 = {0.f, 0.f, 0.f, 0.f};

    // A-fragment from fp32 LDS: 8 consecutive floats -> 8 bf16
#define LDFRAG(dst, p) do {                                                   \
        float4 u_ = *(const float4*)(p);                                      \
        float4 v_ = *(const float4*)((p) + 4);                                \
        dst[0] = f2bf(u_.x); dst[1] = f2bf(u_.y);                             \
        dst[2] = f2bf(u_.z); dst[3] = f2bf(u_.w);                             \
        dst[4] = f2bf(v_.x); dst[5] = f2bf(v_.y);                             \
        dst[6] = f2bf(v_.z); dst[7] = f2bf(v_.w);                             \
    } while (0)

    {   // K-phase 1: agg (k = 0..63)
        short8v b0 = *(const short8v*)&Bp[((0 * 4 + nt) * 64 + lane) * 8];
        short8v b1 = *(const short8v*)&Bp[((1 * 4 + nt) * 64 + lane) * 8];
        short8v a00, a01, a10, a11;
        LDFRAG(a00, &R0[arow]);
        LDFRAG(a01, &R0[arow + 32]);
        LDFRAG(a10, &R0[arow + 16 * PAD]);
        LDFRAG(a11, &R0[arow + 16 * PAD + 32]);
        acc0 = __builtin_amdgcn_mfma_f32_16x16x32_bf16(a00, b0, acc0, 0, 0, 0);
        acc1 = __builtin_amdgcn_mfma_f32_16x16x32_bf16(a10, b0, acc1, 0, 0, 0);
        acc0 = __builtin_amdgcn_mfma_f32_16x16x32_bf16(a01, b1, acc0, 0, 0, 0);
        acc1 = __builtin_amdgcn_mfma_f32_16x16x32_bf16(a11, b1, acc1, 0, 0, 0);
    }
    __syncthreads();          // all agg fragment reads done before overwrite

    // restage this bucket's x rows (fp32, coalesced float4 loads)
    {
        int nn = N - nb0;
        if (nn > BSZ) nn = BSZ;
        const float4* x4 = (const float4*)x;
        for (int idx = t; idx < nn * 16; idx += 512) {
            float4 v = x4[nb0 * 16 + idx];
            float* row = &R0[(idx >> 4) * PAD + (idx & 15) * 4];
            row[0] = v.x; row[1] = v.y; row[2] = v.z; row[3] = v.w;
        }
    }
    __syncthreads();

    {   // K-phase 2: x (k = 64..127)
        short8v b2 = *(const short8v*)&Bp[((2 * 4 + nt) * 64 + lane) * 8];
        short8v b3 = *(const short8v*)&Bp[((3 * 4 + nt) * 64 + lane) * 8];
        short8v a00, a01, a10, a11;
        LDFRAG(a00, &R0[arow]);
        LDFRAG(a01, &R0[arow + 32]);
        LDFRAG(a10, &R0[arow + 16 * PAD]);
        LDFRAG(a11, &R0[arow + 16 * PAD + 32]);
        acc0 = __builtin_amdgcn_mfma_f32_16x16x32_bf16(a00, b2, acc0, 0, 0, 0);
        acc1 = __builtin_amdgcn_mfma_f32_16x16x32_bf16(a10, b2, acc1, 0, 0, 0);
        acc0 = __builtin_amdgcn_mfma_f32_16x16x32_bf16(a01, b3, acc0, 0, 0, 0);
        acc1 = __builtin_amdgcn_mfma_f32_16x16x32_bf16(a11, b3, acc1, 0, 0, 0);
    }
#undef LDFRAG
    __syncthreads();          // all x fragment reads done before xn overwrite

    // epilogue a: xn = x + eps*tanh(h + bc); C cell (row, col) per lane
    {
        const int dcol = nt * 16 + (lane & 15);
        const float bcv = bc[dcol];
#pragma unroll
        for (int mt = 0; mt < 2; ++mt) {
            f32x4 A = mt ? acc1 : acc0;
#pragma unroll
            for (int r = 0; r < 4; ++r) {
                int nloc = mbase + mt * 16 + ((lane >> 4) << 2) + r;
                float h = A[r] + bcv;
                float e2 = __expf(2.0f * h);
                float th = 1.0f - 2.0f / (e2 + 1.0f);
                float xv = R0[nloc * PAD + dcol];
                R0[nloc * PAD + dcol] = xv + EPSILON * th;
            }
        }
    }
    __syncthreads();

    // epilogue b: 8 lanes/node, lane q -> classes 2q, 2q+1
    {
        const int g = t >> 3, q = t & 7;
        const int n = nb0 + g;
        if (n < N) {
            float p0 = blin[2 * q], p1 = blin[2 * q + 1];
#pragma unroll 8
            for (int d = 0; d < DD; ++d) {
                float xv = R0[g * PAD + d];
                p0 = fmaf(xv, wl_sh[(2 * q) * PADW + d], p0);
                p1 = fmaf(xv, wl_sh[(2 * q + 1) * PADW + d], p1);
            }
            float2 o;
            o.x = 1.0f / (1.0f + __expf(-p0));
            o.y = 1.0f / (1.0f + __expf(-p1));
            *(float2*)(out + (size_t)n * CC + 2 * q) = o;
        }
    }
}

// ---------------------------------------------------------------------------
extern "C" void kernel_launch(void* const* d_in, const int* in_sizes, int n_in,
                              void* d_out, int out_size, void* d_ws, size_t ws_size,
                              hipStream_t stream) {
    const int*   ei    = (const int*)d_in[0];
    const float* x     = (const float*)d_in[1];
    const float* Wrel  = (const float*)d_in[2];
    const float* brel  = (const float*)d_in[3];
    const float* Wroot = (const float*)d_in[4];
    const float* Wanti = (const float*)d_in[5];
    const float* banti = (const float*)d_in[6];
    const float* Wlin  = (const float*)d_in[7];
    const float* blin  = (const float*)d_in[8];
    float* out = (float*)d_out;

    const int E = in_sizes[0] / 2;
    const int N = in_sizes[1] / DD;
    const int NB = (N + BSZ - 1) / BSZ;

    // ws: x_q (6.4MB) | binned (12.6MB) | gcnt (64KB) | Bp (16KB) | bc
    unsigned* x_q = (unsigned*)d_ws;
    unsigned* binned = x_q + (size_t)N * (DD / 4);
    int*   gcnt  = (int*)(binned + (size_t)NFB * NREP * SEGF);
    unsigned short* Bp = (unsigned short*)(gcnt + NFB * NREP);
    float* bc    = (float*)(Bp + 16 * 64 * 8);

    hipMemsetAsync(gcnt, 0, NFB * NREP * sizeof(int), stream);
    bin_conv<<<(E + FCHUNK - 1) / FCHUNK, FTHR, 0, stream>>>(
        ei, gcnt, binned, E, x, x_q, N,
        Wrel, Wroot, Wanti, brel, banti, Bp, bc);
    mega<<<NB, 512, 0, stream>>>(x, x_q, gcnt, binned, Bp, bc, Wlin, blin,
                                 out, N);
}

// Round 10
// 149.543 us; speedup vs baseline: 1.0603x; 1.0603x over previous
//
#include <hip/hip_runtime.h>

// N=100000, E=1600000, D=64, C=16
#define DD 64
#define CC 16
#define EPSILON 0.1f
#define GAMMA 0.1f
#define BSH 6            // log2(nodes per fine bucket)
#define BSZ 64
#define CAP 1280         // fine bucket capacity (mean 1024, +8 sigma)
#define MAXBK 2048
#define PAD 68           // fp32 R0 row stride: 272 B, 16B-aligned rows
#define PADW 65
#define CSH 10           // log2(nodes per coarse bucket)
#define MAXNC 128        // >= NC = 98
#define NREP 8           // reservation-counter replicas per coarse bucket
#define SEGC 2560        // CAPC / NREP, per-replica segment capacity
#define CPAD 16          // counter stride in ints (64B line per counter)
#define CAPC 20480       // coarse capacity
#define L1CHUNK 4096     // r10: doubled (391 blocks; chain depth 98 -> 49,
                         // store clusters 21 -> 42 entries)
#define L1THR 512
#define NSLICE 8

typedef float v2f __attribute__((ext_vector_type(2)));
typedef __attribute__((ext_vector_type(8))) short short8v;   // 8 bf16
typedef __attribute__((ext_vector_type(4))) float f32x4;

// fp32 -> bf16 round-to-nearest-even (finite inputs only)
static __device__ inline short f2bf(float f) {
    unsigned u = __builtin_bit_cast(unsigned, f);
    unsigned r = (u + 0x7FFFu + ((u >> 16) & 1u)) >> 16;
    return (short)r;
}

// ---------------------------------------------------------------------------
// K1: coarse binning with 8-way REPLICATED reservation counters (r8) at
// 4096 edges/block (r10). Each block reserves from replica rep=blockIdx&7
// of its bucket counter and stores into the private segment
// binned_c[c*CAPC + rep*SEGC + pos]. LDS histogram -> one reservation per
// (bucket,replica) per block -> direct store. Plus grid-stride x -> fp8
// conversion and (block 0) weight fold into bf16 MFMA-fragment order.
// Pack: src(17) | dst_coarse_local(10) << 17.
__global__ __launch_bounds__(L1THR) void bin_coarse_conv(
        const int* __restrict__ ei, int* __restrict__ gcntc,
        unsigned* __restrict__ binned_c, int E,
        const float* __restrict__ x, unsigned* __restrict__ x_q, int N,
        const float* __restrict__ Wrel, const float* __restrict__ Wroot,
        const float* __restrict__ Wanti, const float* __restrict__ brel,
        const float* __restrict__ banti,
        unsigned short* __restrict__ Bp, float* __restrict__ bc) {
    __shared__ int hist[MAXNC], gbase[MAXNC], cur[MAXNC];
    const int t = threadIdx.x;
    const int rep = blockIdx.x & (NREP - 1);
    if (t < MAXNC) { hist[t] = 0; cur[t] = 0; }
    __syncthreads();
    const int e0 = blockIdx.x * L1CHUNK;
    int srcv[8], dstv[8];
#pragma unroll
    for (int jj = 0; jj < 2; ++jj) {
        int e4 = e0 + 4 * (t + L1THR * jj);
        if (e4 + 4 <= E) {                   // aligned int4 loads
            int4 s4 = *(const int4*)&ei[e4];
            int4 d4 = *(const int4*)&ei[E + e4];
            srcv[4 * jj + 0] = s4.x; srcv[4 * jj + 1] = s4.y;
            srcv[4 * jj + 2] = s4.z; srcv[4 * jj + 3] = s4.w;
            dstv[4 * jj + 0] = d4.x; dstv[4 * jj + 1] = d4.y;
            dstv[4 * jj + 2] = d4.z; dstv[4 * jj + 3] = d4.w;
        } else {
#pragma unroll
            for (int i = 0; i < 4; ++i) {
                int e = e4 + i;
                if (e < E) { srcv[4 * jj + i] = ei[e]; dstv[4 * jj + i] = ei[E + e]; }
                else dstv[4 * jj + i] = -1;
            }
        }
    }
#pragma unroll
    for (int i = 0; i < 8; ++i)
        if (dstv[i] >= 0) atomicAdd(&hist[dstv[i] >> CSH], 1);
    __syncthreads();
    if (t < MAXNC) {
        int h = hist[t];
        gbase[t] = h ? atomicAdd(&gcntc[(t * NREP + rep) * CPAD], h) : 0;
    }
    __syncthreads();
#pragma unroll
    for (int i = 0; i < 8; ++i) {
        if (dstv[i] >= 0) {
            int b = dstv[i] >> CSH;
            int pos = gbase[b] + atomicAdd(&cur[b], 1);
            if (pos < SEGC)
                binned_c[(size_t)b * CAPC + rep * SEGC + pos] =
                    (unsigned)srcv[i] |
                    ((unsigned)(dstv[i] & ((1 << CSH) - 1)) << 17);
        }
    }
    // ---- weight fold -> bf16 fragment-packed (block 0 only) ----
    if (blockIdx.x == 0) {
        for (int idx = t; idx < 16 * 64 * 8; idx += L1THR) {
            int j = idx & 7, l = (idx >> 3) & 63;
            int nt = (idx >> 9) & 3, ks = idx >> 11;
            int k = ks * 32 + ((l >> 4) << 3) + j;
            int d = nt * 16 + (l & 15);
            float v;
            if (k < 64) {
                v = Wrel[d * 64 + k];
            } else {
                int j2 = k - 64;
                v = Wroot[d * 64 + j2] + Wanti[d * 64 + j2] - Wanti[j2 * 64 + d];
                if (d == j2) v -= GAMMA;
            }
            Bp[idx] = (unsigned short)f2bf(v);
        }
        if (t < 64) bc[t] = brel[t] + banti[t];
    }
    // ---- fused x -> fp8 conversion ----
    const float4* x4 = (const float4*)x;
    const int M = N * (DD / 4);
    const int G = gridDim.x * L1THR;
    for (int i = blockIdx.x * L1THR + t; i < M; i += G) {
        float4 a = x4[i];
        int r = __builtin_amdgcn_cvt_pk_fp8_f32(a.x, a.y, 0, false);
        r = __builtin_amdgcn_cvt_pk_fp8_f32(a.z, a.w, r, true);
        x_q[i] = (unsigned)r;
    }
}

// ---------------------------------------------------------------------------
// K2: fine binning. Slice s of coarse bucket c consumes replica segment s.
// Fine entry: src(17) | dst_node_local(6) << 17.
__global__ __launch_bounds__(256) void bin_fine(
        const int* __restrict__ gcntc, const unsigned* __restrict__ binned_c,
        int* __restrict__ gcnt, unsigned* __restrict__ binned) {
    __shared__ int hist[16];
    __shared__ int hbase[16];
    const int t = threadIdx.x;
    const int c = blockIdx.x >> 3, s = blockIdx.x & (NSLICE - 1);
    int cnt = gcntc[(c * NREP + s) * CPAD];
    if (cnt > SEGC) cnt = SEGC;
    if (t < 16) hist[t] = 0;
    __syncthreads();
    const unsigned* bcp = binned_c + (size_t)c * CAPC + s * SEGC;
    unsigned ent[10];
#pragma unroll
    for (int j = 0; j < 10; ++j) {
        int i = t + j * 256;
        ent[j] = (i < cnt) ? bcp[i] : 0xFFFFFFFFu;
        if (ent[j] != 0xFFFFFFFFu) atomicAdd(&hist[ent[j] >> (17 + BSH)], 1);
    }
    __syncthreads();
    if (t < 16) {
        hbase[t] = hist[t] ? atomicAdd(&gcnt[c * 16 + t], hist[t]) : 0;
        hist[t] = 0;
    }
    __syncthreads();
#pragma unroll
    for (int j = 0; j < 10; ++j) {
        if (ent[j] != 0xFFFFFFFFu) {
            unsigned dstc = ent[j] >> 17;
            int f = dstc >> BSH;
            int pos = hbase[f] + atomicAdd(&hist[f], 1);
            if (pos < CAP)
                binned[(size_t)(c * 16 + f) * CAP + pos] =
                    (ent[j] & 0x1FFFF) | ((dstc & (BSZ - 1)) << 17);
        }
    }
}

// ---------------------------------------------------------------------------
// K3 mega (r8 version, byte-identical): CSR build (1-wave prefix scan) +
// fp8 gather (8-deep pipeline) + MFMA dense h = [agg | x] @ B via
// v_mfma_f32_16x16x32_bf16 + fused tanh/residual/projection/sigmoid.
__global__ __launch_bounds__(512, 6) void mega(
        const float* __restrict__ x, const unsigned* __restrict__ x_q,
        const int* __restrict__ gcnt, const unsigned* __restrict__ binned,
        const unsigned short* __restrict__ Bp, const float* __restrict__ bc,
        const float* __restrict__ Wlin, const float* __restrict__ blin,
        float* __restrict__ out, int N) {
    __shared__ float R0[BSZ * PAD];         // 17.4 KB: agg -> x -> xn
    __shared__ float wl_sh[CC * PADW];      // 4.2 KB
    __shared__ int csr[CAP];                // 5.1 KB
    __shared__ int deg[BSZ], offs[BSZ], cur[BSZ];

    const int t = threadIdx.x;
    const int b = blockIdx.x;
    const int nb0 = b << BSH;
    int cnt = gcnt[b];
    if (cnt > CAP) cnt = CAP;
    const unsigned* bl = binned + (size_t)b * CAP;

#pragma unroll
    for (int i = 0; i < 2; ++i) {
        int idx = t + 512 * i;
        wl_sh[(idx >> 6) * PADW + (idx & 63)] = Wlin[idx];
    }
    if (t < BSZ) deg[t] = 0;
    __syncthreads();
    for (int i = t; i < cnt; i += 512) atomicAdd(&deg[bl[i] >> 17], 1);
    __syncthreads();
    if (t < 64) {                           // single-wave prefix scan
        int v = deg[t];
#pragma unroll
        for (int off = 1; off < 64; off <<= 1) {
            int u = __shfl_up(v, off, 64);
            if (t >= off) v += u;
        }
        offs[t] = v - deg[t];
        cur[t] = v - deg[t];
    }
    __syncthreads();
    for (int i = t; i < cnt; i += 512) {
        unsigned en = bl[i];
        int pos = atomicAdd(&cur[en >> 17], 1);
        csr[pos] = (int)(en & 0x1FFFF);
    }
    __syncthreads();

    // fp8 gather, 8-deep pipeline
    {
        const int g = t >> 3, q = t & 7;
        const uint2* xq2 = (const uint2*)x_q;   // 8 fp8 per slot; row = 8 slots
        const int i0 = offs[g], dc = deg[g];
        float a[8];
#pragma unroll
        for (int r = 0; r < 8; ++r) a[r] = 0.f;
        int i = 0;
        for (; i + 8 <= dc; i += 8) {
            int s0 = csr[i0 + i + 0], s1 = csr[i0 + i + 1];
            int s2 = csr[i0 + i + 2], s3 = csr[i0 + i + 3];
            int s4 = csr[i0 + i + 4], s5 = csr[i0 + i + 5];
            int s6 = csr[i0 + i + 6], s7 = csr[i0 + i + 7];
            uint2 v0 = xq2[s0 * 8 + q];
            uint2 v1 = xq2[s1 * 8 + q];
            uint2 v2 = xq2[s2 * 8 + q];
            uint2 v3 = xq2[s3 * 8 + q];
            uint2 v4 = xq2[s4 * 8 + q];
            uint2 v5 = xq2[s5 * 8 + q];
            uint2 v6 = xq2[s6 * 8 + q];
            uint2 v7 = xq2[s7 * 8 + q];
            v2f f;
#define ACC8(v)                                                               \
            f = __builtin_amdgcn_cvt_pk_f32_fp8((v).x, false); a[0] += f.x; a[1] += f.y; \
            f = __builtin_amdgcn_cvt_pk_f32_fp8((v).x, true);  a[2] += f.x; a[3] += f.y; \
            f = __builtin_amdgcn_cvt_pk_f32_fp8((v).y, false); a[4] += f.x; a[5] += f.y; \
            f = __builtin_amdgcn_cvt_pk_f32_fp8((v).y, true);  a[6] += f.x; a[7] += f.y;
            ACC8(v0); ACC8(v1); ACC8(v2); ACC8(v3);
            ACC8(v4); ACC8(v5); ACC8(v6); ACC8(v7);
        }
        for (; i < dc; ++i) {
            int s0 = csr[i0 + i];
            uint2 v0 = xq2[s0 * 8 + q];
            v2f f;
            ACC8(v0);
#undef ACC8
        }
        float* row = &R0[g * PAD + 8 * q];
#pragma unroll
        for (int r = 0; r < 8; ++r) row[r] = a[r];
    }
    __syncthreads();

    // ---- MFMA dense ----
    const int lane = t & 63;
    const int w = t >> 6;                   // wave 0..7
    const int nt = w & 3, mbase = (w >> 2) * 32;
    const int arow = (mbase + (lane & 15)) * PAD + ((lane >> 4) << 3);
    f32x4 acc0 = {0.f, 0.f, 0.f, 0.f}, acc1 = {0.f, 0.f, 0.f, 0.f};

    // A-fragment from fp32 LDS: 8 consecutive floats -> 8 bf16
#define LDFRAG(dst, p) do {                                                   \
        float4 u_ = *(const float4*)(p);                                      \
        float4 v_ = *(const float4*)((p) + 4);                                \
        dst[0] = f2bf(u_.x); dst[1] = f2bf(u_.y);                             \
        dst[2] = f2bf(u_.z); dst[3] = f2bf(u_.w);                             \
        dst[4] = f2bf(v_.x); dst[5] = f2bf(v_.y);                             \
        dst[6] = f2bf(v_.z); dst[7] = f2bf(v_.w);                             \
    } while (0)

    {   // K-phase 1: agg (k = 0..63)
        short8v b0 = *(const short8v*)&Bp[((0 * 4 + nt) * 64 + lane) * 8];
        short8v b1 = *(const short8v*)&Bp[((1 * 4 + nt) * 64 + lane) * 8];
        short8v a00, a01, a10, a11;
        LDFRAG(a00, &R0[arow]);
        LDFRAG(a01, &R0[arow + 32]);
        LDFRAG(a10, &R0[arow + 16 * PAD]);
        LDFRAG(a11, &R0[arow + 16 * PAD + 32]);
        acc0 = __builtin_amdgcn_mfma_f32_16x16x32_bf16(a00, b0, acc0, 0, 0, 0);
        acc1 = __builtin_amdgcn_mfma_f32_16x16x32_bf16(a10, b0, acc1, 0, 0, 0);
        acc0 = __builtin_amdgcn_mfma_f32_16x16x32_bf16(a01, b1, acc0, 0, 0, 0);
        acc1 = __builtin_amdgcn_mfma_f32_16x16x32_bf16(a11, b1, acc1, 0, 0, 0);
    }
    __syncthreads();          // all agg fragment reads done before overwrite

    // restage this bucket's x rows (fp32, coalesced float4 loads)
    {
        int nn = N - nb0;
        if (nn > BSZ) nn = BSZ;
        const float4* x4 = (const float4*)x;
        for (int idx = t; idx < nn * 16; idx += 512) {
            float4 v = x4[nb0 * 16 + idx];
            float* row = &R0[(idx >> 4) * PAD + (idx & 15) * 4];
            row[0] = v.x; row[1] = v.y; row[2] = v.z; row[3] = v.w;
        }
    }
    __syncthreads();

    {   // K-phase 2: x (k = 64..127)
        short8v b2 = *(const short8v*)&Bp[((2 * 4 + nt) * 64 + lane) * 8];
        short8v b3 = *(const short8v*)&Bp[((3 * 4 + nt) * 64 + lane) * 8];
        short8v a00, a01, a10, a11;
        LDFRAG(a00, &R0[arow]);
        LDFRAG(a01, &R0[arow + 32]);
        LDFRAG(a10, &R0[arow + 16 * PAD]);
        LDFRAG(a11, &R0[arow + 16 * PAD + 32]);
        acc0 = __builtin_amdgcn_mfma_f32_16x16x32_bf16(a00, b2, acc0, 0, 0, 0);
        acc1 = __builtin_amdgcn_mfma_f32_16x16x32_bf16(a10, b2, acc1, 0, 0, 0);
        acc0 = __builtin_amdgcn_mfma_f32_16x16x32_bf16(a01, b3, acc0, 0, 0, 0);
        acc1 = __builtin_amdgcn_mfma_f32_16x16x32_bf16(a11, b3, acc1, 0, 0, 0);
    }
#undef LDFRAG
    __syncthreads();          // all x fragment reads done before xn overwrite

    // epilogue a: xn = x + eps*tanh(h + bc); C cell (row, col) per lane
    {
        const int dcol = nt * 16 + (lane & 15);
        const float bcv = bc[dcol];
#pragma unroll
        for (int mt = 0; mt < 2; ++mt) {
            f32x4 A = mt ? acc1 : acc0;
#pragma unroll
            for (int r = 0; r < 4; ++r) {
                int nloc = mbase + mt * 16 + ((lane >> 4) << 2) + r;
                float h = A[r] + bcv;
                float e2 = __expf(2.0f * h);
                float th = 1.0f - 2.0f / (e2 + 1.0f);
                float xv = R0[nloc * PAD + dcol];
                R0[nloc * PAD + dcol] = xv + EPSILON * th;
            }
        }
    }
    __syncthreads();

    // epilogue b: 8 lanes/node, lane q -> classes 2q, 2q+1
    {
        const int g = t >> 3, q = t & 7;
        const int n = nb0 + g;
        if (n < N) {
            float p0 = blin[2 * q], p1 = blin[2 * q + 1];
#pragma unroll 8
            for (int d = 0; d < DD; ++d) {
                float xv = R0[g * PAD + d];
                p0 = fmaf(xv, wl_sh[(2 * q) * PADW + d], p0);
                p1 = fmaf(xv, wl_sh[(2 * q + 1) * PADW + d], p1);
            }
            float2 o;
            o.x = 1.0f / (1.0f + __expf(-p0));
            o.y = 1.0f / (1.0f + __expf(-p1));
            *(float2*)(out + (size_t)n * CC + 2 * q) = o;
        }
    }
}

// ---------------------------------------------------------------------------
extern "C" void kernel_launch(void* const* d_in, const int* in_sizes, int n_in,
                              void* d_out, int out_size, void* d_ws, size_t ws_size,
                              hipStream_t stream) {
    const int*   ei    = (const int*)d_in[0];
    const float* x     = (const float*)d_in[1];
    const float* Wrel  = (const float*)d_in[2];
    const float* brel  = (const float*)d_in[3];
    const float* Wroot = (const float*)d_in[4];
    const float* Wanti = (const float*)d_in[5];
    const float* banti = (const float*)d_in[6];
    const float* Wlin  = (const float*)d_in[7];
    const float* blin  = (const float*)d_in[8];
    float* out = (float*)d_out;

    const int E = in_sizes[0] / 2;
    const int N = in_sizes[1] / DD;
    const int NC = (N + (1 << CSH) - 1) >> CSH;

    // ws: x_q | binned_c | binned | gcntc(replicated,padded) | gcnt | Bp | bc
    unsigned* x_q = (unsigned*)d_ws;
    unsigned* binned_c = x_q + (size_t)N * (DD / 4);
    unsigned* binned = binned_c + (size_t)MAXNC * CAPC;
    int*   gcntc = (int*)(binned + (size_t)MAXBK * CAP);
    int*   gcnt  = gcntc + MAXNC * NREP * CPAD;
    unsigned short* Bp = (unsigned short*)(gcnt + MAXBK);
    float* bc    = (float*)(Bp + 16 * 64 * 8);

    hipMemsetAsync(gcntc, 0, (MAXNC * NREP * CPAD + MAXBK) * sizeof(int), stream);
    bin_coarse_conv<<<(E + L1CHUNK - 1) / L1CHUNK, L1THR, 0, stream>>>(
        ei, gcntc, binned_c, E, x, x_q, N,
        Wrel, Wroot, Wanti, brel, banti, Bp, bc);
    bin_fine<<<NC * NSLICE, 256, 0, stream>>>(gcntc, binned_c, gcnt, binned);
    mega<<<NC * 16, 512, 0, stream>>>(x, x_q, gcnt, binned, Bp, bc, Wlin, blin,
                                      out, N);
}